// Round 1
// baseline (2110.360 us; speedup 1.0000x reference)
//
#include <hip/hip_runtime.h>
#include <hip/hip_bf16.h>

#define N_NODES 100000
#define N_TYPES 10
#define N_EDGES 3200000
#define HIDDEN 256
#define EMBED 128
#define N_PAIRS 100000

// ---------------------------------------------------------------------------
// Kernel 1: row_ptr from sorted rows via per-node lower_bound (no atomics)
// ---------------------------------------------------------------------------
__global__ void build_rowptr_k(const int* __restrict__ rows, int* __restrict__ rp,
                               int n_nodes, int n_edges) {
    int n = blockIdx.x * blockDim.x + threadIdx.x;
    if (n > n_nodes) return;
    int lo = 0, hi = n_edges;
    while (lo < hi) {
        int mid = (lo + hi) >> 1;
        if (rows[mid] < n) lo = mid + 1; else hi = mid;
    }
    rp[n] = lo;
}

// ---------------------------------------------------------------------------
// Kernel 2: spmm1 fused with x = node_emb + type_emb[node_type_ids]
// one block per node, 256 threads = one lane per feature (coalesced 1KB gathers)
// ---------------------------------------------------------------------------
__global__ void spmm_fused_x_k(const int* __restrict__ rp, const int* __restrict__ cols,
                               const float* __restrict__ vals,
                               const float* __restrict__ node_emb,
                               const float* __restrict__ type_emb,
                               const int* __restrict__ ntype,
                               float* __restrict__ out) {
    int n = blockIdx.x;
    int f = threadIdx.x;
    int e0 = rp[n], e1 = rp[n + 1];
    float acc = 0.f;
    for (int e = e0; e < e1; ++e) {
        int c = cols[e];
        float v = vals[e];
        int t = ntype[c];
        acc += v * (node_emb[c * HIDDEN + f] + type_emb[t * HIDDEN + f]);
    }
    out[n * HIDDEN + f] = acc;
}

// ---------------------------------------------------------------------------
// Kernel 3: plain spmm (for layer 2)
// ---------------------------------------------------------------------------
__global__ void spmm_k(const int* __restrict__ rp, const int* __restrict__ cols,
                       const float* __restrict__ vals,
                       const float* __restrict__ x, float* __restrict__ out) {
    int n = blockIdx.x;
    int f = threadIdx.x;
    int e0 = rp[n], e1 = rp[n + 1];
    float acc = 0.f;
    for (int e = e0; e < e1; ++e) {
        acc += vals[e] * x[cols[e] * HIDDEN + f];
    }
    out[n * HIDDEN + f] = acc;
}

// ---------------------------------------------------------------------------
// Kernel 4: fp32 tiled GEMM  C = [relu](A @ W + bias)
// A: MxK row-major, W: KxN row-major. BM=64, BN=64, BK=16, 256 thr, 4x4/thread
// ---------------------------------------------------------------------------
template <bool RELU>
__global__ void gemm_bias_k(const float* __restrict__ A, const float* __restrict__ W,
                            const float* __restrict__ bias, float* __restrict__ C,
                            int M, int N, int K) {
    __shared__ float As[16][64];   // As[k][m]
    __shared__ float Bs[16][64];   // Bs[k][n]

    int t  = threadIdx.x;
    int tx = t & 15;               // 0..15 -> 4 cols each
    int ty = t >> 4;               // 0..15 -> 4 rows each
    int m0 = blockIdx.x * 64;
    int n0 = blockIdx.y * 64;

    float acc[4][4] = {};

    for (int k0 = 0; k0 < K; k0 += 16) {
        // A tile: thread loads float4 at (row = t>>2, k = (t&3)*4), store transposed
        {
            int m  = t >> 2;
            int kq = (t & 3) * 4;
            float4 av = make_float4(0.f, 0.f, 0.f, 0.f);
            int row = m0 + m;
            if (row < M) av = *(const float4*)&A[(size_t)row * K + k0 + kq];
            As[kq + 0][m] = av.x;
            As[kq + 1][m] = av.y;
            As[kq + 2][m] = av.z;
            As[kq + 3][m] = av.w;
        }
        // W tile: thread loads float4 at (k = t>>4, n = (t&15)*4)
        {
            int kr = t >> 4;
            int nq = (t & 15) * 4;
            float4 wv = *(const float4*)&W[(size_t)(k0 + kr) * N + n0 + nq];
            *(float4*)&Bs[kr][nq] = wv;
        }
        __syncthreads();

#pragma unroll
        for (int k = 0; k < 16; ++k) {
            float4 a = *(const float4*)&As[k][ty * 4];
            float4 b = *(const float4*)&Bs[k][tx * 4];
            float av[4] = {a.x, a.y, a.z, a.w};
            float bv[4] = {b.x, b.y, b.z, b.w};
#pragma unroll
            for (int i = 0; i < 4; ++i)
#pragma unroll
                for (int j = 0; j < 4; ++j)
                    acc[i][j] += av[i] * bv[j];
        }
        __syncthreads();
    }

    // epilogue
#pragma unroll
    for (int i = 0; i < 4; ++i) {
        int row = m0 + ty * 4 + i;
        if (row >= M) break;
#pragma unroll
        for (int j = 0; j < 4; ++j) {
            int col = n0 + tx * 4 + j;
            float v = acc[i][j] + bias[col];
            if (RELU) v = v > 0.f ? v : 0.f;
            C[(size_t)row * N + col] = v;
        }
    }
}

// ---------------------------------------------------------------------------
// Kernel 5: fused pair scorer
// feat = [z[s] | z[d] | z[s]*z[d]]  (K=384) @ Wp1 (384x128) + bp1, relu,
// then dot with Wp2 (128) + bp2 -> out[p]
// BM=64 pairs, BN=128 (full), BK=16, 256 thr, 4x8 per thread
// ---------------------------------------------------------------------------
__global__ void scorer_k(const float* __restrict__ z, const int* __restrict__ pairs,
                         const float* __restrict__ Wp1, const float* __restrict__ bp1,
                         const float* __restrict__ Wp2, const float* __restrict__ bp2,
                         float* __restrict__ out, int P) {
    __shared__ float As[16][64];    // feat^T tile
    __shared__ float Bs[16][128];   // Wp1 tile
    __shared__ int   sidx[64], didx[64];
    __shared__ float red[64][16];

    int p0 = blockIdx.x * 64;
    int t  = threadIdx.x;

    if (t < 64) {
        int p  = p0 + t;
        int pp = p < P ? p : P - 1;
        sidx[t] = pairs[pp];
        didx[t] = pairs[P + pp];
    }
    __syncthreads();

    int tx = t & 15;   // cols tx*8 .. +7
    int ty = t >> 4;   // rows ty*4 .. +3
    float acc[4][8] = {};

    for (int k0 = 0; k0 < 3 * EMBED; k0 += 16) {
        // feat tile: thread handles pair p = t>>2, k-quad = (t&3)*4
        {
            int p  = t >> 2;
            int kq = k0 + (t & 3) * 4;
            int s = sidx[p], d = didx[p];
            float4 fv;
            if (kq < EMBED) {
                fv = *(const float4*)&z[(size_t)s * EMBED + kq];
            } else if (kq < 2 * EMBED) {
                fv = *(const float4*)&z[(size_t)d * EMBED + kq - EMBED];
            } else {
                float4 a = *(const float4*)&z[(size_t)s * EMBED + kq - 2 * EMBED];
                float4 b = *(const float4*)&z[(size_t)d * EMBED + kq - 2 * EMBED];
                fv = make_float4(a.x * b.x, a.y * b.y, a.z * b.z, a.w * b.w);
            }
            int kk = (t & 3) * 4;
            As[kk + 0][p] = fv.x;
            As[kk + 1][p] = fv.y;
            As[kk + 2][p] = fv.z;
            As[kk + 3][p] = fv.w;
        }
        // Wp1 tile: k = t>>4, cols (t&15)*8 (two float4)
        {
            int kr = t >> 4;
            int nc = (t & 15) * 8;
            float4 w0 = *(const float4*)&Wp1[(size_t)(k0 + kr) * 128 + nc];
            float4 w1 = *(const float4*)&Wp1[(size_t)(k0 + kr) * 128 + nc + 4];
            *(float4*)&Bs[kr][nc]     = w0;
            *(float4*)&Bs[kr][nc + 4] = w1;
        }
        __syncthreads();

#pragma unroll
        for (int k = 0; k < 16; ++k) {
            float4 a  = *(const float4*)&As[k][ty * 4];
            float4 b0 = *(const float4*)&Bs[k][tx * 8];
            float4 b1 = *(const float4*)&Bs[k][tx * 8 + 4];
            float av[4] = {a.x, a.y, a.z, a.w};
            float bv[8] = {b0.x, b0.y, b0.z, b0.w, b1.x, b1.y, b1.z, b1.w};
#pragma unroll
            for (int i = 0; i < 4; ++i)
#pragma unroll
                for (int j = 0; j < 8; ++j)
                    acc[i][j] += av[i] * bv[j];
        }
        __syncthreads();
    }

    // epilogue: relu(acc + bp1) dot Wp2, reduce over tx
    float w2[8], b1v[8];
#pragma unroll
    for (int j = 0; j < 8; ++j) {
        w2[j]  = Wp2[tx * 8 + j];
        b1v[j] = bp1[tx * 8 + j];
    }
#pragma unroll
    for (int i = 0; i < 4; ++i) {
        float partial = 0.f;
#pragma unroll
        for (int j = 0; j < 8; ++j) {
            float v = acc[i][j] + b1v[j];
            v = v > 0.f ? v : 0.f;
            partial += v * w2[j];
        }
        red[ty * 4 + i][tx] = partial;
    }
    __syncthreads();
    if (t < 64) {
        float sum = 0.f;
#pragma unroll
        for (int j = 0; j < 16; ++j) sum += red[t][j];
        if (p0 + t < P) out[p0 + t] = sum + bp2[0];
    }
}

// ---------------------------------------------------------------------------
// Launch
// ---------------------------------------------------------------------------
extern "C" void kernel_launch(void* const* d_in, const int* in_sizes, int n_in,
                              void* d_out, int out_size, void* d_ws, size_t ws_size,
                              hipStream_t stream) {
    const int*   node_type_ids = (const int*)d_in[0];
    const int*   rows          = (const int*)d_in[1];
    const int*   cols          = (const int*)d_in[2];
    const float* edge_vals     = (const float*)d_in[3];
    const int*   pairs         = (const int*)d_in[4];
    const float* node_emb      = (const float*)d_in[5];
    const float* type_emb      = (const float*)d_in[6];
    const float* W1            = (const float*)d_in[7];
    const float* b1            = (const float*)d_in[8];
    const float* W2            = (const float*)d_in[9];
    const float* b2            = (const float*)d_in[10];
    const float* Wp1           = (const float*)d_in[11];
    const float* bp1           = (const float*)d_in[12];
    const float* Wp2           = (const float*)d_in[13];
    const float* bp2           = (const float*)d_in[14];
    float* out = (float*)d_out;

    char* ws = (char*)d_ws;
    const size_t RP_OFF = 0;                                   // (N+1) ints
    const size_t S1_OFF = 1 << 20;                             // 1 MB offset
    const size_t FEAT_BYTES = (size_t)N_NODES * HIDDEN * 4;    // 102.4 MB
    const size_t H_OFF  = S1_OFF + FEAT_BYTES;
    const size_t Z_OFF  = H_OFF + FEAT_BYTES;

    int*   rp = (int*)(ws + RP_OFF);
    float* s1 = (float*)(ws + S1_OFF);   // spmm1 out; later reused for spmm2 out
    float* h  = (float*)(ws + H_OFF);
    float* z  = (float*)(ws + Z_OFF);

    // 1. row_ptr
    build_rowptr_k<<<(N_NODES + 256) / 256, 256, 0, stream>>>(rows, rp, N_NODES, N_EDGES);

    // 2. s1 = spmm(x) with x fused
    spmm_fused_x_k<<<N_NODES, HIDDEN, 0, stream>>>(rp, cols, edge_vals,
                                                   node_emb, type_emb, node_type_ids, s1);

    // 3. h = relu(s1 @ W1 + b1)
    {
        dim3 grid((N_NODES + 63) / 64, HIDDEN / 64);
        gemm_bias_k<true><<<grid, 256, 0, stream>>>(s1, W1, b1, h, N_NODES, HIDDEN, HIDDEN);
    }

    // 4. s2 = spmm(h)  (into s1's buffer)
    spmm_k<<<N_NODES, HIDDEN, 0, stream>>>(rp, cols, edge_vals, h, s1);

    // 5. z = s2 @ W2 + b2
    {
        dim3 grid((N_NODES + 63) / 64, EMBED / 64);
        gemm_bias_k<false><<<grid, 256, 0, stream>>>(s1, W2, b2, z, N_NODES, EMBED, HIDDEN);
    }

    // 6. scorer
    scorer_k<<<(N_PAIRS + 63) / 64, 256, 0, stream>>>(z, pairs, Wp1, bp1, Wp2, bp2,
                                                      out, N_PAIRS);
}

// Round 2
// 822.626 us; speedup vs baseline: 2.5654x; 2.5654x over previous
//
#include <hip/hip_runtime.h>
#include <hip/hip_bf16.h>

#define N_NODES 100000
#define N_TYPES 10
#define N_EDGES 3200000
#define HIDDEN 256
#define EMBED 128
#define N_PAIRS 100000

typedef _Float16 half4v __attribute__((ext_vector_type(4)));
typedef _Float16 half2v __attribute__((ext_vector_type(2)));
typedef _Float16 half8v __attribute__((ext_vector_type(8)));
typedef float floatx4 __attribute__((ext_vector_type(4)));

#define GLOBAL_AS __attribute__((address_space(1)))
#define LDS_AS __attribute__((address_space(3)))

static __device__ __forceinline__ void async_copy16(const void* g, void* lds) {
    __builtin_amdgcn_global_load_lds((const GLOBAL_AS unsigned int*)g,
                                     (LDS_AS unsigned int*)(void*)lds, 16, 0, 0);
}

// ---------------------------------------------------------------------------
// row_ptr from sorted rows (binary search, no atomics)
// ---------------------------------------------------------------------------
__global__ void build_rowptr_k(const int* __restrict__ rows, int* __restrict__ rp,
                               int n_nodes, int n_edges) {
    int n = blockIdx.x * blockDim.x + threadIdx.x;
    if (n > n_nodes) return;
    int lo = 0, hi = n_edges;
    while (lo < hi) {
        int mid = (lo + hi) >> 1;
        if (rows[mid] < n) lo = mid + 1; else hi = mid;
    }
    rp[n] = lo;
}

// ---------------------------------------------------------------------------
// x16[n][f] = fp16(node_emb[n][f] + type_emb[type[n]][f]) -- 4 elems/thread
// ---------------------------------------------------------------------------
__global__ void build_x16_k(const float* __restrict__ node_emb,
                            const float* __restrict__ type_emb,
                            const int* __restrict__ ntype,
                            _Float16* __restrict__ x16) {
    int idx = blockIdx.x * blockDim.x + threadIdx.x;   // one per 4 elements
    int n  = idx >> 6;                                  // 64 quads per row
    if (n >= N_NODES) return;
    int f4 = (idx & 63) * 4;
    int t = ntype[n];
    float4 a = *(const float4*)&node_emb[(size_t)n * HIDDEN + f4];
    float4 b = *(const float4*)&type_emb[(size_t)t * HIDDEN + f4];
    half4v o;
    o.x = (_Float16)(a.x + b.x);
    o.y = (_Float16)(a.y + b.y);
    o.z = (_Float16)(a.z + b.z);
    o.w = (_Float16)(a.w + b.w);
    *(half4v*)&x16[(size_t)n * HIDDEN + f4] = o;
}

// ---------------------------------------------------------------------------
// Wt[n][k] = fp16(W[k][n])  (transpose so GEMM B-operand is [N][K] row-major)
// ---------------------------------------------------------------------------
__global__ void transpose_w_k(const float* __restrict__ W, _Float16* __restrict__ Wt,
                              int K, int N) {
    int idx = blockIdx.x * blockDim.x + threadIdx.x;   // idx = n*K + k
    if (idx >= K * N) return;
    int k = idx & (256 - 1);   // K == 256 always here
    int n = idx >> 8;
    Wt[idx] = (_Float16)W[(size_t)k * N + n];
}

// ---------------------------------------------------------------------------
// spmm1: s1[n][0:256] (fp16) = sum_e val[e] * x16[cols[e]][0:256]
// one wave per node, lane holds 4 features (8B gathers, 512B/wave/edge)
// ---------------------------------------------------------------------------
__global__ void spmm1_k(const int* __restrict__ rp, const int* __restrict__ cols,
                        const float* __restrict__ vals,
                        const _Float16* __restrict__ x16, _Float16* __restrict__ s1) {
    int wave = threadIdx.x >> 6, lane = threadIdx.x & 63;
    int n = blockIdx.x * 4 + wave;
    int e0 = rp[n], e1 = rp[n + 1];
    int fo = lane * 4;
    float4 acc = make_float4(0.f, 0.f, 0.f, 0.f);
    int e = e0;
    for (; e + 2 <= e1; e += 2) {
        int c0 = cols[e], c1 = cols[e + 1];
        float v0 = vals[e], v1 = vals[e + 1];
        half4v h0 = *(const half4v*)&x16[(size_t)c0 * HIDDEN + fo];
        half4v h1 = *(const half4v*)&x16[(size_t)c1 * HIDDEN + fo];
        acc.x += v0 * (float)h0.x + v1 * (float)h1.x;
        acc.y += v0 * (float)h0.y + v1 * (float)h1.y;
        acc.z += v0 * (float)h0.z + v1 * (float)h1.z;
        acc.w += v0 * (float)h0.w + v1 * (float)h1.w;
    }
    if (e < e1) {
        int c0 = cols[e];
        float v0 = vals[e];
        half4v h0 = *(const half4v*)&x16[(size_t)c0 * HIDDEN + fo];
        acc.x += v0 * (float)h0.x;
        acc.y += v0 * (float)h0.y;
        acc.z += v0 * (float)h0.z;
        acc.w += v0 * (float)h0.w;
    }
    half4v o;
    o.x = (_Float16)acc.x; o.y = (_Float16)acc.y;
    o.z = (_Float16)acc.z; o.w = (_Float16)acc.w;
    *(half4v*)&s1[(size_t)n * HIDDEN + fo] = o;
}

// ---------------------------------------------------------------------------
// spmm2: z[n][0:128] (fp32) = sum_e val[e] * g16[cols[e]][0:128] + b2
// one wave per node, lane holds 2 features (4B gathers, 256B/wave/edge)
// ---------------------------------------------------------------------------
__global__ void spmm2_k(const int* __restrict__ rp, const int* __restrict__ cols,
                        const float* __restrict__ vals,
                        const _Float16* __restrict__ g16,
                        const float* __restrict__ b2, float* __restrict__ z) {
    int wave = threadIdx.x >> 6, lane = threadIdx.x & 63;
    int n = blockIdx.x * 4 + wave;
    int e0 = rp[n], e1 = rp[n + 1];
    int fo = lane * 2;
    float ax = 0.f, ay = 0.f;
    int e = e0;
    for (; e + 2 <= e1; e += 2) {
        int c0 = cols[e], c1 = cols[e + 1];
        float v0 = vals[e], v1 = vals[e + 1];
        half2v h0 = *(const half2v*)&g16[(size_t)c0 * EMBED + fo];
        half2v h1 = *(const half2v*)&g16[(size_t)c1 * EMBED + fo];
        ax += v0 * (float)h0.x + v1 * (float)h1.x;
        ay += v0 * (float)h0.y + v1 * (float)h1.y;
    }
    if (e < e1) {
        int c0 = cols[e];
        float v0 = vals[e];
        half2v h0 = *(const half2v*)&g16[(size_t)c0 * EMBED + fo];
        ax += v0 * (float)h0.x;
        ay += v0 * (float)h0.y;
    }
    float2 o;
    o.x = ax + b2[fo];
    o.y = ay + b2[fo + 1];
    *(float2*)&z[(size_t)n * EMBED + fo] = o;
}

// ---------------------------------------------------------------------------
// fp16 MFMA GEMM: C16 = [relu](A @ Bt^T + bias), A [M,256] fp16, Bt [N,256] fp16
// 128x128 tile, BK=32, 256 thr (4 waves, each 64x64), global_load_lds staging
// ---------------------------------------------------------------------------
template <bool RELU, bool BIAS>
__global__ void gemm16_k(const _Float16* __restrict__ A,
                         const _Float16* __restrict__ Bt,
                         const float* __restrict__ bias,
                         _Float16* __restrict__ C,
                         int M, int N) {
    const int K = 256;
    __shared__ _Float16 As[128 * 32];
    __shared__ _Float16 Bs[128 * 32];

    int t = threadIdx.x;
    int lane = t & 63;
    int wave = t >> 6;
    int quad = lane >> 4;
    int m16 = lane & 15;
    int wr = wave >> 1, wc = wave & 1;
    int m0 = blockIdx.x * 128;
    int n0 = blockIdx.y * 128;

    int srow = t >> 2;            // 0..63
    int skoff = (t & 3) * 8;      // 0,8,16,24

    floatx4 acc[4][4];
#pragma unroll
    for (int i = 0; i < 4; ++i)
#pragma unroll
        for (int j = 0; j < 4; ++j)
            acc[i][j] = (floatx4)0.f;

    for (int k0 = 0; k0 < K; k0 += 32) {
        // stage A rows 0..127 of tile (clamped), Bt rows n0..n0+127 (exact)
        int ra0 = m0 + srow;       if (ra0 >= M) ra0 = M - 1;
        int ra1 = m0 + srow + 64;  if (ra1 >= M) ra1 = M - 1;
        async_copy16(&A[(size_t)ra0 * K + k0 + skoff], &As[srow * 32 + skoff]);
        async_copy16(&A[(size_t)ra1 * K + k0 + skoff], &As[(srow + 64) * 32 + skoff]);
        async_copy16(&Bt[(size_t)(n0 + srow) * K + k0 + skoff], &Bs[srow * 32 + skoff]);
        async_copy16(&Bt[(size_t)(n0 + srow + 64) * K + k0 + skoff], &Bs[(srow + 64) * 32 + skoff]);
        __syncthreads();

        half8v aF[4], bF[4];
#pragma unroll
        for (int i = 0; i < 4; ++i)
            aF[i] = *(const half8v*)&As[(wr * 64 + i * 16 + m16) * 32 + quad * 8];
#pragma unroll
        for (int j = 0; j < 4; ++j)
            bF[j] = *(const half8v*)&Bs[(wc * 64 + j * 16 + m16) * 32 + quad * 8];
#pragma unroll
        for (int i = 0; i < 4; ++i)
#pragma unroll
            for (int j = 0; j < 4; ++j)
                acc[i][j] = __builtin_amdgcn_mfma_f32_16x16x32_f16(aF[i], bF[j], acc[i][j], 0, 0, 0);
        __syncthreads();
    }

    // epilogue: D col=lane&15, row=quad*4+r (measured m89/m91)
#pragma unroll
    for (int i = 0; i < 4; ++i) {
#pragma unroll
        for (int j = 0; j < 4; ++j) {
            int gr = m0 + wr * 64 + i * 16 + quad * 4;
            int gc = n0 + wc * 64 + j * 16 + m16;
            float bv = BIAS ? bias[gc] : 0.f;
#pragma unroll
            for (int r = 0; r < 4; ++r) {
                int row = gr + r;
                if (row < M) {
                    float v = acc[i][j][r] + bv;
                    if (RELU) v = v > 0.f ? v : 0.f;
                    C[(size_t)row * N + gc] = (_Float16)v;
                }
            }
        }
    }
}

// ---------------------------------------------------------------------------
// fused pair scorer (fp32, z fp32 [N,128])
// ---------------------------------------------------------------------------
__global__ void scorer_k(const float* __restrict__ z, const int* __restrict__ pairs,
                         const float* __restrict__ Wp1, const float* __restrict__ bp1,
                         const float* __restrict__ Wp2, const float* __restrict__ bp2,
                         float* __restrict__ out, int P) {
    __shared__ float As[16][64];
    __shared__ float Bs[16][128];
    __shared__ int   sidx[64], didx[64];
    __shared__ float red[64][16];

    int p0 = blockIdx.x * 64;
    int t  = threadIdx.x;

    if (t < 64) {
        int p  = p0 + t;
        int pp = p < P ? p : P - 1;
        sidx[t] = pairs[pp];
        didx[t] = pairs[P + pp];
    }
    __syncthreads();

    int tx = t & 15;
    int ty = t >> 4;
    float acc[4][8] = {};

    for (int k0 = 0; k0 < 3 * EMBED; k0 += 16) {
        {
            int p  = t >> 2;
            int kq = k0 + (t & 3) * 4;
            int s = sidx[p], d = didx[p];
            float4 fv;
            if (kq < EMBED) {
                fv = *(const float4*)&z[(size_t)s * EMBED + kq];
            } else if (kq < 2 * EMBED) {
                fv = *(const float4*)&z[(size_t)d * EMBED + kq - EMBED];
            } else {
                float4 a = *(const float4*)&z[(size_t)s * EMBED + kq - 2 * EMBED];
                float4 b = *(const float4*)&z[(size_t)d * EMBED + kq - 2 * EMBED];
                fv = make_float4(a.x * b.x, a.y * b.y, a.z * b.z, a.w * b.w);
            }
            int kk = (t & 3) * 4;
            As[kk + 0][p] = fv.x;
            As[kk + 1][p] = fv.y;
            As[kk + 2][p] = fv.z;
            As[kk + 3][p] = fv.w;
        }
        {
            int kr = t >> 4;
            int nc = (t & 15) * 8;
            float4 w0 = *(const float4*)&Wp1[(size_t)(k0 + kr) * 128 + nc];
            float4 w1 = *(const float4*)&Wp1[(size_t)(k0 + kr) * 128 + nc + 4];
            *(float4*)&Bs[kr][nc]     = w0;
            *(float4*)&Bs[kr][nc + 4] = w1;
        }
        __syncthreads();

#pragma unroll
        for (int k = 0; k < 16; ++k) {
            float4 a  = *(const float4*)&As[k][ty * 4];
            float4 b0 = *(const float4*)&Bs[k][tx * 8];
            float4 b1 = *(const float4*)&Bs[k][tx * 8 + 4];
            float av[4] = {a.x, a.y, a.z, a.w};
            float bv[8] = {b0.x, b0.y, b0.z, b0.w, b1.x, b1.y, b1.z, b1.w};
#pragma unroll
            for (int i = 0; i < 4; ++i)
#pragma unroll
                for (int j = 0; j < 8; ++j)
                    acc[i][j] += av[i] * bv[j];
        }
        __syncthreads();
    }

    float w2[8], b1v[8];
#pragma unroll
    for (int j = 0; j < 8; ++j) {
        w2[j]  = Wp2[tx * 8 + j];
        b1v[j] = bp1[tx * 8 + j];
    }
#pragma unroll
    for (int i = 0; i < 4; ++i) {
        float partial = 0.f;
#pragma unroll
        for (int j = 0; j < 8; ++j) {
            float v = acc[i][j] + b1v[j];
            v = v > 0.f ? v : 0.f;
            partial += v * w2[j];
        }
        red[ty * 4 + i][tx] = partial;
    }
    __syncthreads();
    if (t < 64) {
        float sum = 0.f;
#pragma unroll
        for (int j = 0; j < 16; ++j) sum += red[t][j];
        if (p0 + t < P) out[p0 + t] = sum + bp2[0];
    }
}

// ---------------------------------------------------------------------------
// Launch
// ---------------------------------------------------------------------------
extern "C" void kernel_launch(void* const* d_in, const int* in_sizes, int n_in,
                              void* d_out, int out_size, void* d_ws, size_t ws_size,
                              hipStream_t stream) {
    const int*   node_type_ids = (const int*)d_in[0];
    const int*   rows          = (const int*)d_in[1];
    const int*   cols          = (const int*)d_in[2];
    const float* edge_vals     = (const float*)d_in[3];
    const int*   pairs         = (const int*)d_in[4];
    const float* node_emb      = (const float*)d_in[5];
    const float* type_emb      = (const float*)d_in[6];
    const float* W1            = (const float*)d_in[7];
    const float* b1            = (const float*)d_in[8];
    const float* W2            = (const float*)d_in[9];
    const float* b2            = (const float*)d_in[10];
    const float* Wp1           = (const float*)d_in[11];
    const float* bp1           = (const float*)d_in[12];
    const float* Wp2           = (const float*)d_in[13];
    const float* bp2           = (const float*)d_in[14];
    float* out = (float*)d_out;

    const size_t MB = 1ull << 20;
    char* ws = (char*)d_ws;
    int*      rp   = (int*)(ws);
    _Float16* x16  = (_Float16*)(ws + 4 * MB);
    _Float16* s1   = (_Float16*)(ws + 56 * MB);
    _Float16* h16  = (_Float16*)(ws + 108 * MB);
    _Float16* g16  = (_Float16*)(ws + 160 * MB);
    float*    z    = (float*)(ws + 186 * MB);
    _Float16* W1t  = (_Float16*)(ws + 238 * MB);
    _Float16* W2t  = (_Float16*)(ws + 239 * MB);

    // prep
    build_rowptr_k<<<(N_NODES + 256) / 256, 256, 0, stream>>>(rows, rp, N_NODES, N_EDGES);
    build_x16_k<<<(N_NODES * 64 + 255) / 256, 256, 0, stream>>>(node_emb, type_emb,
                                                                node_type_ids, x16);
    transpose_w_k<<<(HIDDEN * HIDDEN + 255) / 256, 256, 0, stream>>>(W1, W1t, HIDDEN, HIDDEN);
    transpose_w_k<<<(HIDDEN * EMBED + 255) / 256, 256, 0, stream>>>(W2, W2t, HIDDEN, EMBED);

    // s1 = spmm(x16)  [fp16]
    spmm1_k<<<N_NODES / 4, 256, 0, stream>>>(rp, cols, edge_vals, x16, s1);

    // h = relu(s1 @ W1 + b1)  [fp16, MFMA]
    {
        dim3 grid((N_NODES + 127) / 128, HIDDEN / 128);
        gemm16_k<true, true><<<grid, 256, 0, stream>>>(s1, W1t, b1, h16, N_NODES, HIDDEN);
    }

    // g = h @ W2  [fp16, MFMA]  (z = spmm(g) + b2 by linearity)
    {
        dim3 grid((N_NODES + 127) / 128, EMBED / 128);
        gemm16_k<false, false><<<grid, 256, 0, stream>>>(h16, W2t, nullptr, g16, N_NODES, EMBED);
    }

    // z = spmm(g) + b2  [fp32]
    spmm2_k<<<N_NODES / 4, 256, 0, stream>>>(rp, cols, edge_vals, g16, b2, z);

    // scorer
    scorer_k<<<(N_PAIRS + 63) / 64, 256, 0, stream>>>(z, pairs, Wp1, bp1, Wp2, bp2,
                                                      out, N_PAIRS);
}

// Round 3
// 632.638 us; speedup vs baseline: 3.3358x; 1.3003x over previous
//
#include <hip/hip_runtime.h>
#include <hip/hip_bf16.h>

#define N_NODES 100000
#define N_TYPES 10
#define N_EDGES 3200000
#define HIDDEN 256
#define EMBED 128
#define N_PAIRS 100000

typedef _Float16 half2v __attribute__((ext_vector_type(2)));
typedef _Float16 half4v __attribute__((ext_vector_type(4)));
typedef _Float16 half8v __attribute__((ext_vector_type(8)));
typedef float floatx4 __attribute__((ext_vector_type(4)));

#define GLOBAL_AS __attribute__((address_space(1)))
#define LDS_AS __attribute__((address_space(3)))

static __device__ __forceinline__ void async_copy16(const void* g, void* lds) {
    __builtin_amdgcn_global_load_lds((const GLOBAL_AS unsigned int*)g,
                                     (LDS_AS unsigned int*)(void*)lds, 16, 0, 0);
}

// ---------------------------------------------------------------------------
// row_ptr from sorted rows (binary search, no atomics)
// ---------------------------------------------------------------------------
__global__ void build_rowptr_k(const int* __restrict__ rows, int* __restrict__ rp,
                               int n_nodes, int n_edges) {
    int n = blockIdx.x * blockDim.x + threadIdx.x;
    if (n > n_nodes) return;
    int lo = 0, hi = n_edges;
    while (lo < hi) {
        int mid = (lo + hi) >> 1;
        if (rows[mid] < n) lo = mid + 1; else hi = mid;
    }
    rp[n] = lo;
}

// ---------------------------------------------------------------------------
// x16[n][f] = fp16(node_emb[n][f] + type_emb[type[n]][f])
// ---------------------------------------------------------------------------
__global__ void build_x16_k(const float* __restrict__ node_emb,
                            const float* __restrict__ type_emb,
                            const int* __restrict__ ntype,
                            _Float16* __restrict__ x16) {
    int idx = blockIdx.x * blockDim.x + threadIdx.x;
    int n  = idx >> 6;
    if (n >= N_NODES) return;
    int f4 = (idx & 63) * 4;
    int t = ntype[n];
    float4 a = *(const float4*)&node_emb[(size_t)n * HIDDEN + f4];
    float4 b = *(const float4*)&type_emb[(size_t)t * HIDDEN + f4];
    half4v o;
    o.x = (_Float16)(a.x + b.x);
    o.y = (_Float16)(a.y + b.y);
    o.z = (_Float16)(a.z + b.z);
    o.w = (_Float16)(a.w + b.w);
    *(half4v*)&x16[(size_t)n * HIDDEN + f4] = o;
}

// ---------------------------------------------------------------------------
// Wt[n][k] = fp16(W[k][n])  for K=256 weights (W1, W2)
// ---------------------------------------------------------------------------
__global__ void transpose_w_k(const float* __restrict__ W, _Float16* __restrict__ Wt,
                              int K, int N) {
    int idx = blockIdx.x * blockDim.x + threadIdx.x;   // idx = n*256 + k
    if (idx >= K * N) return;
    int k = idx & 255;
    int n = idx >> 8;
    Wt[idx] = (_Float16)W[(size_t)k * N + n];
}

// Wp1 [384,128] -> Wp1t [128][384] fp16
__global__ void transpose_wp1_k(const float* __restrict__ W, _Float16* __restrict__ Wt) {
    int k = threadIdx.x;   // 0..383
    int n = blockIdx.x;    // 0..127
    Wt[n * 384 + k] = (_Float16)W[(size_t)k * EMBED + n];
}

// ---------------------------------------------------------------------------
// spmm1: s1[n][0:256] fp16 = sum_e val[e] * x16[cols[e]][:]
// one wave/node, lane = 4 feats (8B gathers); edge loop unrolled 8x for MLP
// ---------------------------------------------------------------------------
__global__ void spmm1_k(const int* __restrict__ rp, const int* __restrict__ cols,
                        const float* __restrict__ vals,
                        const _Float16* __restrict__ x16, _Float16* __restrict__ s1) {
    int wave = threadIdx.x >> 6, lane = threadIdx.x & 63;
    int n = blockIdx.x * 4 + wave;
    int e0 = rp[n], e1 = rp[n + 1];
    int fo = lane * 4;
    float4 acc = make_float4(0.f, 0.f, 0.f, 0.f);
    int e = e0;
    for (; e + 8 <= e1; e += 8) {
        int c[8]; float v[8];
#pragma unroll
        for (int i = 0; i < 8; ++i) { c[i] = cols[e + i]; v[i] = vals[e + i]; }
        half4v h[8];
#pragma unroll
        for (int i = 0; i < 8; ++i)
            h[i] = *(const half4v*)&x16[(size_t)c[i] * HIDDEN + fo];
#pragma unroll
        for (int i = 0; i < 8; ++i) {
            acc.x += v[i] * (float)h[i].x;
            acc.y += v[i] * (float)h[i].y;
            acc.z += v[i] * (float)h[i].z;
            acc.w += v[i] * (float)h[i].w;
        }
    }
    for (; e < e1; ++e) {
        int c0 = cols[e]; float v0 = vals[e];
        half4v h0 = *(const half4v*)&x16[(size_t)c0 * HIDDEN + fo];
        acc.x += v0 * (float)h0.x;
        acc.y += v0 * (float)h0.y;
        acc.z += v0 * (float)h0.z;
        acc.w += v0 * (float)h0.w;
    }
    half4v o;
    o.x = (_Float16)acc.x; o.y = (_Float16)acc.y;
    o.z = (_Float16)acc.z; o.w = (_Float16)acc.w;
    *(half4v*)&s1[(size_t)n * HIDDEN + fo] = o;
}

// ---------------------------------------------------------------------------
// spmm2: z16[n][0:128] fp16 = sum_e val[e] * g16[cols[e]][:] + b2
// one wave/node, lane = 2 feats (4B gathers); unrolled 8x
// ---------------------------------------------------------------------------
__global__ void spmm2_k(const int* __restrict__ rp, const int* __restrict__ cols,
                        const float* __restrict__ vals,
                        const _Float16* __restrict__ g16,
                        const float* __restrict__ b2, _Float16* __restrict__ z16) {
    int wave = threadIdx.x >> 6, lane = threadIdx.x & 63;
    int n = blockIdx.x * 4 + wave;
    int e0 = rp[n], e1 = rp[n + 1];
    int fo = lane * 2;
    float ax = 0.f, ay = 0.f;
    int e = e0;
    for (; e + 8 <= e1; e += 8) {
        int c[8]; float v[8];
#pragma unroll
        for (int i = 0; i < 8; ++i) { c[i] = cols[e + i]; v[i] = vals[e + i]; }
        half2v h[8];
#pragma unroll
        for (int i = 0; i < 8; ++i)
            h[i] = *(const half2v*)&g16[(size_t)c[i] * EMBED + fo];
#pragma unroll
        for (int i = 0; i < 8; ++i) {
            ax += v[i] * (float)h[i].x;
            ay += v[i] * (float)h[i].y;
        }
    }
    for (; e < e1; ++e) {
        int c0 = cols[e]; float v0 = vals[e];
        half2v h0 = *(const half2v*)&g16[(size_t)c0 * EMBED + fo];
        ax += v0 * (float)h0.x;
        ay += v0 * (float)h0.y;
    }
    half2v o;
    o.x = (_Float16)(ax + b2[fo]);
    o.y = (_Float16)(ay + b2[fo + 1]);
    *(half2v*)&z16[(size_t)n * EMBED + fo] = o;
}

// ---------------------------------------------------------------------------
// fp16 MFMA GEMM: C16 = [relu](A @ Bt^T + bias), A [M,256], Bt [N,256]
// 128x128 tile, BK=32, 256 thr, global_load_lds width-16 staging
// ---------------------------------------------------------------------------
template <bool RELU, bool BIAS>
__global__ void gemm16_k(const _Float16* __restrict__ A,
                         const _Float16* __restrict__ Bt,
                         const float* __restrict__ bias,
                         _Float16* __restrict__ C,
                         int M, int N) {
    const int K = 256;
    __shared__ _Float16 As[128 * 32];
    __shared__ _Float16 Bs[128 * 32];

    int t = threadIdx.x;
    int lane = t & 63;
    int wave = t >> 6;
    int quad = lane >> 4;
    int m16 = lane & 15;
    int wr = wave >> 1, wc = wave & 1;
    int m0 = blockIdx.x * 128;
    int n0 = blockIdx.y * 128;

    int srow = t >> 2;
    int skoff = (t & 3) * 8;

    floatx4 acc[4][4];
#pragma unroll
    for (int i = 0; i < 4; ++i)
#pragma unroll
        for (int j = 0; j < 4; ++j)
            acc[i][j] = (floatx4)0.f;

    for (int k0 = 0; k0 < K; k0 += 32) {
        int ra0 = m0 + srow;       if (ra0 >= M) ra0 = M - 1;
        int ra1 = m0 + srow + 64;  if (ra1 >= M) ra1 = M - 1;
        async_copy16(&A[(size_t)ra0 * K + k0 + skoff], &As[srow * 32 + skoff]);
        async_copy16(&A[(size_t)ra1 * K + k0 + skoff], &As[(srow + 64) * 32 + skoff]);
        async_copy16(&Bt[(size_t)(n0 + srow) * K + k0 + skoff], &Bs[srow * 32 + skoff]);
        async_copy16(&Bt[(size_t)(n0 + srow + 64) * K + k0 + skoff], &Bs[(srow + 64) * 32 + skoff]);
        __syncthreads();

        half8v aF[4], bF[4];
#pragma unroll
        for (int i = 0; i < 4; ++i)
            aF[i] = *(const half8v*)&As[(wr * 64 + i * 16 + m16) * 32 + quad * 8];
#pragma unroll
        for (int j = 0; j < 4; ++j)
            bF[j] = *(const half8v*)&Bs[(wc * 64 + j * 16 + m16) * 32 + quad * 8];
#pragma unroll
        for (int i = 0; i < 4; ++i)
#pragma unroll
            for (int j = 0; j < 4; ++j)
                acc[i][j] = __builtin_amdgcn_mfma_f32_16x16x32_f16(aF[i], bF[j], acc[i][j], 0, 0, 0);
        __syncthreads();
    }

#pragma unroll
    for (int i = 0; i < 4; ++i) {
#pragma unroll
        for (int j = 0; j < 4; ++j) {
            int gr = m0 + wr * 64 + i * 16 + quad * 4;
            int gc = n0 + wc * 64 + j * 16 + m16;
            float bv = BIAS ? bias[gc] : 0.f;
#pragma unroll
            for (int r = 0; r < 4; ++r) {
                int row = gr + r;
                if (row < M) {
                    float v = acc[i][j][r] + bv;
                    if (RELU) v = v > 0.f ? v : 0.f;
                    C[(size_t)row * N + gc] = (_Float16)v;
                }
            }
        }
    }
}

// ---------------------------------------------------------------------------
// MFMA fp16 pair scorer: 128 pairs/block, N=128, K=384 in 3 regions of 128
// feat = [z[s] | z[d] | z[s]*z[d]]; out[p] = relu(feat@Wp1+bp1) . Wp2 + bp2
// ---------------------------------------------------------------------------
__global__ __launch_bounds__(256) void scorer_mfma_k(
        const _Float16* __restrict__ z16, const int* __restrict__ pairs,
        const _Float16* __restrict__ Wp1t, const float* __restrict__ bp1,
        const float* __restrict__ Wp2, const float* __restrict__ bp2,
        float* __restrict__ out, int P) {
    __shared__ _Float16 Fs[128][136];   // feat chunk [pair][k], +8 pad
    __shared__ _Float16 Ws[128][136];   // Wp1t chunk [n][k]
    __shared__ int sidx[128], didx[128];
    __shared__ float red[128][2];

    int t  = threadIdx.x;
    int p0 = blockIdx.x * 128;

    if (t < 128) {
        int p = p0 + t;
        if (p >= P) p = P - 1;
        sidx[t] = pairs[p];
        didx[t] = pairs[P + p];
    }
    __syncthreads();

    int lane = t & 63, wave = t >> 6;
    int quad = lane >> 4, m16 = lane & 15;
    int wr = wave >> 1, wc = wave & 1;

    floatx4 acc[4][4];
#pragma unroll
    for (int i = 0; i < 4; ++i)
#pragma unroll
        for (int j = 0; j < 4; ++j)
            acc[i][j] = (floatx4)0.f;

    int pr = t & 127;          // staging row (pair / n)
    int kh = (t >> 7) * 64;    // k-half offset 0 / 64

    for (int r = 0; r < 3; ++r) {
        // stage feat region
        {
            const _Float16* zs = &z16[(size_t)sidx[pr] * EMBED + kh];
            const _Float16* zd = &z16[(size_t)didx[pr] * EMBED + kh];
            half8v f[8];
            if (r == 0) {
#pragma unroll
                for (int i = 0; i < 8; ++i) f[i] = *(const half8v*)&zs[i * 8];
            } else if (r == 1) {
#pragma unroll
                for (int i = 0; i < 8; ++i) f[i] = *(const half8v*)&zd[i * 8];
            } else {
#pragma unroll
                for (int i = 0; i < 8; ++i) {
                    half8v a = *(const half8v*)&zs[i * 8];
                    half8v b = *(const half8v*)&zd[i * 8];
                    f[i] = a * b;
                }
            }
#pragma unroll
            for (int i = 0; i < 8; ++i)
                *(half8v*)&Fs[pr][kh + i * 8] = f[i];
        }
        // stage Wp1t region
        {
            const _Float16* wsrc = &Wp1t[(size_t)pr * 384 + r * 128 + kh];
#pragma unroll
            for (int i = 0; i < 8; ++i)
                *(half8v*)&Ws[pr][kh + i * 8] = *(const half8v*)&wsrc[i * 8];
        }
        __syncthreads();

#pragma unroll
        for (int k0 = 0; k0 < 128; k0 += 32) {
            half8v aF[4], bF[4];
#pragma unroll
            for (int i = 0; i < 4; ++i)
                aF[i] = *(const half8v*)&Fs[wr * 64 + i * 16 + m16][k0 + quad * 8];
#pragma unroll
            for (int j = 0; j < 4; ++j)
                bF[j] = *(const half8v*)&Ws[wc * 64 + j * 16 + m16][k0 + quad * 8];
#pragma unroll
            for (int i = 0; i < 4; ++i)
#pragma unroll
                for (int j = 0; j < 4; ++j)
                    acc[i][j] = __builtin_amdgcn_mfma_f32_16x16x32_f16(aF[i], bF[j], acc[i][j], 0, 0, 0);
        }
        __syncthreads();
    }

    // epilogue: relu(acc + bp1) . Wp2, shfl-reduce across the 16 col lanes
    float w2v[4], b1v[4];
#pragma unroll
    for (int j = 0; j < 4; ++j) {
        int col = wc * 64 + j * 16 + m16;
        w2v[j] = Wp2[col];
        b1v[j] = bp1[col];
    }
#pragma unroll
    for (int i = 0; i < 4; ++i) {
#pragma unroll
        for (int rr = 0; rr < 4; ++rr) {
            float partial = 0.f;
#pragma unroll
            for (int j = 0; j < 4; ++j) {
                float v = acc[i][j][rr] + b1v[j];
                v = v > 0.f ? v : 0.f;
                partial += v * w2v[j];
            }
#pragma unroll
            for (int off = 1; off < 16; off <<= 1)
                partial += __shfl_xor(partial, off, 64);
            if (m16 == 0)
                red[wr * 64 + i * 16 + quad * 4 + rr][wc] = partial;
        }
    }
    __syncthreads();
    if (t < 128) {
        int p = p0 + t;
        if (p < P) out[p] = red[t][0] + red[t][1] + bp2[0];
    }
}

// ---------------------------------------------------------------------------
// Launch
// ---------------------------------------------------------------------------
extern "C" void kernel_launch(void* const* d_in, const int* in_sizes, int n_in,
                              void* d_out, int out_size, void* d_ws, size_t ws_size,
                              hipStream_t stream) {
    const int*   node_type_ids = (const int*)d_in[0];
    const int*   rows          = (const int*)d_in[1];
    const int*   cols          = (const int*)d_in[2];
    const float* edge_vals     = (const float*)d_in[3];
    const int*   pairs         = (const int*)d_in[4];
    const float* node_emb      = (const float*)d_in[5];
    const float* type_emb      = (const float*)d_in[6];
    const float* W1            = (const float*)d_in[7];
    const float* b1            = (const float*)d_in[8];
    const float* W2            = (const float*)d_in[9];
    const float* b2            = (const float*)d_in[10];
    const float* Wp1           = (const float*)d_in[11];
    const float* bp1           = (const float*)d_in[12];
    const float* Wp2           = (const float*)d_in[13];
    const float* bp2           = (const float*)d_in[14];
    float* out = (float*)d_out;

    const size_t MB = 1ull << 20;
    char* ws = (char*)d_ws;
    int*      rp   = (int*)(ws);
    _Float16* x16  = (_Float16*)(ws + 4 * MB);
    _Float16* s1   = (_Float16*)(ws + 56 * MB);
    _Float16* h16  = (_Float16*)(ws + 108 * MB);
    _Float16* g16  = (_Float16*)(ws + 160 * MB);
    _Float16* z16  = (_Float16*)(ws + 186 * MB);
    _Float16* W1t  = (_Float16*)(ws + 212 * MB);
    _Float16* W2t  = (_Float16*)(ws + 213 * MB);
    _Float16* Wp1t = (_Float16*)(ws + 214 * MB);

    // prep
    build_rowptr_k<<<(N_NODES + 256) / 256, 256, 0, stream>>>(rows, rp, N_NODES, N_EDGES);
    build_x16_k<<<(N_NODES * 64 + 255) / 256, 256, 0, stream>>>(node_emb, type_emb,
                                                                node_type_ids, x16);
    transpose_w_k<<<(HIDDEN * HIDDEN + 255) / 256, 256, 0, stream>>>(W1, W1t, HIDDEN, HIDDEN);
    transpose_w_k<<<(HIDDEN * EMBED + 255) / 256, 256, 0, stream>>>(W2, W2t, HIDDEN, EMBED);
    transpose_wp1_k<<<EMBED, 3 * EMBED, 0, stream>>>(Wp1, Wp1t);

    // s1 = spmm(x16)
    spmm1_k<<<N_NODES / 4, 256, 0, stream>>>(rp, cols, edge_vals, x16, s1);

    // h = relu(s1 @ W1 + b1)
    {
        dim3 grid((N_NODES + 127) / 128, HIDDEN / 128);
        gemm16_k<true, true><<<grid, 256, 0, stream>>>(s1, W1t, b1, h16, N_NODES, HIDDEN);
    }

    // g = h @ W2   (z = spmm(g) + b2 by linearity)
    {
        dim3 grid((N_NODES + 127) / 128, EMBED / 128);
        gemm16_k<false, false><<<grid, 256, 0, stream>>>(h16, W2t, nullptr, g16, N_NODES, EMBED);
    }

    // z16 = spmm(g) + b2
    spmm2_k<<<N_NODES / 4, 256, 0, stream>>>(rp, cols, edge_vals, g16, b2, z16);

    // scorer
    scorer_mfma_k<<<(N_PAIRS + 127) / 128, 256, 0, stream>>>(z16, pairs, Wp1t, bp1,
                                                             Wp2, bp2, out, N_PAIRS);
}